// Round 1
// baseline (106.722 us; speedup 1.0000x reference)
//
#include <hip/hip_runtime.h>

// SignedDistance: B=1, F=20908, Q=1e6.
// Outputs concatenated flat (float32):
//   [0,Q)      signed_distances
//   [Q,4Q)     residual_norm  (Q x 3)
//   [4Q,7Q)    closest_points (Q x 3)
//   [7Q,8Q)    closest_faces  (as float values)
//   [8Q,11Q)   clipped bcs    (Q x 3)
__global__ void SignedDistance_57698590655052_kernel(
    const float* __restrict__ tri,      // (F,3,3) flat
    const float* __restrict__ fnorm,    // (F,3) flat
    const float* __restrict__ pts,      // (Q,3) flat
    const int*   __restrict__ faces,    // (Q,)
    const float* __restrict__ bcs_in,   // (Q,3) flat
    float* __restrict__ out,
    int Q)
{
    int q = blockIdx.x * blockDim.x + threadIdx.x;
    if (q >= Q) return;

    int face = faces[q];

    // clip bcs to [0,1]
    float b0 = fminf(fmaxf(bcs_in[3*q + 0], 0.0f), 1.0f);
    float b1 = fminf(fmaxf(bcs_in[3*q + 1], 0.0f), 1.0f);
    float b2 = fminf(fmaxf(bcs_in[3*q + 2], 0.0f), 1.0f);

    // gather triangle (v,c) flat = v*3+c ; cp[c] = sum_v tri[v][c]*bc[v]
    const float* t = tri + 9 * face;
    float t00 = t[0], t01 = t[1], t02 = t[2];
    float t10 = t[3], t11 = t[4], t12 = t[5];
    float t20 = t[6], t21 = t[7], t22 = t[8];

    float cp0 = t00 * b0 + t10 * b1 + t20 * b2;
    float cp1 = t01 * b0 + t11 * b1 + t21 * b2;
    float cp2 = t02 * b0 + t12 * b1 + t22 * b2;

    float p0 = pts[3*q + 0];
    float p1 = pts[3*q + 1];
    float p2 = pts[3*q + 2];

    float r0 = cp0 - p0;
    float r1 = cp1 - p1;
    float r2 = cp2 - p2;

    float ss   = r0*r0 + r1*r1 + r2*r2;
    float dist = sqrtf(ss);
    float nrm  = (dist == 0.0f) ? 1.0f : dist;
    float inv  = 1.0f / nrm;

    float rn0 = r0 * inv;
    float rn1 = r1 * inv;
    float rn2 = r2 * inv;

    float n0 = fnorm[3*face + 0];
    float n1 = fnorm[3*face + 1];
    float n2 = fnorm[3*face + 2];

    float dp   = rn0*n0 + rn1*n1 + rn2*n2;
    float sign = (dp > 0.0f) ? -1.0f : 1.0f;

    // writes
    out[q] = sign * dist;

    float* rn_out = out + (size_t)Q;
    rn_out[3*q + 0] = rn0;
    rn_out[3*q + 1] = rn1;
    rn_out[3*q + 2] = rn2;

    float* cp_out = out + (size_t)4 * Q;
    cp_out[3*q + 0] = cp0;
    cp_out[3*q + 1] = cp1;
    cp_out[3*q + 2] = cp2;

    out[(size_t)7 * Q + q] = (float)face;

    float* bc_out = out + (size_t)8 * Q;
    bc_out[3*q + 0] = b0;
    bc_out[3*q + 1] = b1;
    bc_out[3*q + 2] = b2;
}

extern "C" void kernel_launch(void* const* d_in, const int* in_sizes, int n_in,
                              void* d_out, int out_size, void* d_ws, size_t ws_size,
                              hipStream_t stream) {
    const float* tri    = (const float*)d_in[0];  // (B,F,3,3)
    const float* fnorm  = (const float*)d_in[1];  // (B,F,3)
    const float* pts    = (const float*)d_in[2];  // (B,Q,3)
    const int*   faces  = (const int*)d_in[3];    // (B,Q)
    const float* bcs    = (const float*)d_in[4];  // (B,Q,3)

    int Q = in_sizes[3];  // B*Q with B=1

    int block = 256;
    int grid  = (Q + block - 1) / block;
    SignedDistance_57698590655052_kernel<<<grid, block, 0, stream>>>(
        tri, fnorm, pts, faces, bcs, (float*)d_out, Q);
}